// Round 1
// baseline (463.274 us; speedup 1.0000x reference)
//
#include <hip/hip_runtime.h>
#include <hip/hip_bf16.h>
#include <math.h>

typedef __bf16 bf16_t;
typedef __attribute__((ext_vector_type(4))) __bf16 bf16x4;
typedef __attribute__((ext_vector_type(8))) __bf16 bf16x8;
typedef __attribute__((ext_vector_type(4))) float floatx4;

#define SCALE 0.17677669529663689f
#define MFMA __builtin_amdgcn_mfma_f32_16x16x32_bf16

// ---------------------------------------------------------------------------
// LayerNorm + cyclic shift (-3,-3) + window partition; fp32 in -> bf16 out
// ---------------------------------------------------------------------------
__global__ __launch_bounds__(256)
void ln_window(const float* __restrict__ x, const float* __restrict__ g,
               const float* __restrict__ bta, bf16_t* __restrict__ xw)
{
    const int wv = threadIdx.x >> 6, lane = threadIdx.x & 63;
    const int t = blockIdx.x * 4 + wv;            // token id, < 100352
    const float* row = x + (size_t)t * 192;
    float v0 = row[lane];
    float v1 = row[lane + 64];
    float v2 = row[lane + 128];
    float s  = v0 + v1 + v2;
    float sq = v0 * v0 + v1 * v1 + v2 * v2;
#pragma unroll
    for (int off = 32; off > 0; off >>= 1) {
        s  += __shfl_down(s, off);
        sq += __shfl_down(sq, off);
    }
    s = __shfl(s, 0); sq = __shfl(sq, 0);
    float mu  = s * (1.0f / 192.0f);
    float var = sq * (1.0f / 192.0f) - mu * mu;
    float inv = rsqrtf(var + 1e-5f);

    int b = t / 3136, p = t - b * 3136;
    int hh = p / 56, ww = p - hh * 56;
    int hs = hh - 3; if (hs < 0) hs += 56;
    int ws = ww - 3; if (ws < 0) ws += 56;
    int wh = hs / 7, ii = hs - wh * 7;
    int wwi = ws / 7, jj = ws - wwi * 7;
    size_t orow = ((size_t)(b * 64 + wh * 8 + wwi) * 49 + ii * 7 + jj) * 192;

    xw[orow + lane]       = (bf16_t)((v0 - mu) * inv * g[lane]       + bta[lane]);
    xw[orow + lane + 64]  = (bf16_t)((v1 - mu) * inv * g[lane + 64]  + bta[lane + 64]);
    xw[orow + lane + 128] = (bf16_t)((v2 - mu) * inv * g[lane + 128] + bta[lane + 128]);
}

// ---------------------------------------------------------------------------
// Weight fp32 -> bf16 conversion (qkv_w | proj_w | lin_w concatenated)
// ---------------------------------------------------------------------------
__global__ __launch_bounds__(256)
void convert_weights(const float* __restrict__ a, const float* __restrict__ b,
                     const float* __restrict__ c, bf16_t* __restrict__ out)
{
    int i = blockIdx.x * 256 + threadIdx.x;   // 184320 total
    if (i < 110592)       out[i] = (bf16_t)a[i];
    else if (i < 147456)  out[i] = (bf16_t)b[i - 110592];
    else                  out[i] = (bf16_t)c[i - 147456];
}

// ---------------------------------------------------------------------------
// Pre-combine rel-pos bias + shift mask into C-fragment-ordered table:
// cb2[wh=win*6+h][mt][lane][nt*4+r]  (bf16); j>=49 -> -1e30
// ---------------------------------------------------------------------------
__global__ __launch_bounds__(256)
void build_cb2(const float* __restrict__ table, const int* __restrict__ rpi,
               const float* __restrict__ mask, bf16_t* __restrict__ cb2)
{
    int i = blockIdx.x * 256 + threadIdx.x;   // 1,572,864 total
    int idx = i & 15, lane = (i >> 4) & 63, mt = (i >> 10) & 3, wh = i >> 12;
    int win = wh / 6, h = wh - win * 6;
    int nt = idx >> 2, r = idx & 3;
    int m = mt * 16 + ((lane >> 4)) * 4 + r;
    int j = nt * 16 + (lane & 15);
    float v;
    if (j >= 49)      v = -1e30f;
    else if (m >= 49) v = 0.0f;
    else              v = table[rpi[m * 49 + j] * 6 + h] + mask[win * 2401 + m * 49 + j];
    cb2[i] = (bf16_t)v;
}

// ---------------------------------------------------------------------------
// Fused per-window kernel: qkv GEMM + attention + proj GEMM.
// One block per window (2048), 6 waves, wave h = head h.
//
// REGISTER-PRESSURE RESTRUCTURE (occupancy was 1 block/CU at ~192 unified
// regs/wave): q,k,v computed in ONE pass over two 32-token halves so the X
// fragments live only one K-iteration (8 regs instead of 96 held across the
// whole kernel); v held in 32 persistent accumulator regs; q/k staged per
// half.  Peak unified liveness ~115 regs -> 4 waves/SIMD -> 2 blocks/CU.
//
// LDS: 6 regions of 5120 bf16 (10.24 KB) = 60 KB total (2 blocks fit).
//   region/head: [q 64x40 | k 64x40]
//   after qf/kf pulled: vT [32][72] overlays the k half (packed b64 stores);
//   P stored in two 32-key halves [64][40] overlaying the q half, pf frags
//   pulled between halves (per-wave DS in-order => no barrier needed).
// ctx transposes through lds[0..12800) (2 block barriers) into proj.
// ---------------------------------------------------------------------------
__global__ __launch_bounds__(384, 4)
void fused_window(const bf16_t* __restrict__ xw, const bf16_t* __restrict__ wcvt,
                  const float* __restrict__ qkv_b, const float* __restrict__ proj_b,
                  const bf16_t* __restrict__ cb2, bf16_t* __restrict__ pob)
{
    __shared__ __align__(16) bf16_t lds[30720];     // 6 * 5120
    const int tid = threadIdx.x;
    const int h = tid >> 6;                          // head 0..5
    const int lane = tid & 63;
    const int quad = lane >> 4, lr = lane & 15;
    const int w = blockIdx.x;                        // window id 0..2047
    const int wh = (w & 63) * 6 + h;
    bf16_t* R  = lds + h * 5120;                     // q rows [64][40]
    bf16_t* RK = R + 2560;                           // k rows [64][40] -> vT [32][72]

    const bf16_t* xb = xw + (size_t)w * 49 * 192;

    // ---- Phase A: q,k,v = X @ W  in two 32-token halves ----
    floatx4 va[4][2];                                // v accumulators, persistent
#pragma unroll
    for (int mt = 0; mt < 4; ++mt) { va[mt][0] = floatx4{0.f,0.f,0.f,0.f}; va[mt][1] = floatx4{0.f,0.f,0.f,0.f}; }

#pragma unroll
    for (int half = 0; half < 2; ++half) {
        floatx4 aq[2][2], ak[2][2];
#pragma unroll
        for (int mt2 = 0; mt2 < 2; ++mt2)
#pragma unroll
            for (int nt = 0; nt < 2; ++nt) {
                aq[mt2][nt] = floatx4{0.f,0.f,0.f,0.f};
                ak[mt2][nt] = floatx4{0.f,0.f,0.f,0.f};
            }
#pragma unroll
        for (int ks = 0; ks < 6; ++ks) {
            const bf16_t* xr = xb + (size_t)(half * 32 + lr) * 192 + ks * 32 + quad * 8;
            bf16x8 x0 = *(const bf16x8*)(xr);
            bf16x8 x1 = *(const bf16x8*)(xr + 16 * 192);
            const bf16_t* wr = wcvt + (size_t)(h * 32 + lr) * 192 + ks * 32 + quad * 8;
            bf16x8 wq0 = *(const bf16x8*)(wr);
            bf16x8 wq1 = *(const bf16x8*)(wr + 16 * 192);
            bf16x8 wk0 = *(const bf16x8*)(wr + 192 * 192);
            bf16x8 wk1 = *(const bf16x8*)(wr + 208 * 192);
            bf16x8 wv0 = *(const bf16x8*)(wr + 384 * 192);
            bf16x8 wv1 = *(const bf16x8*)(wr + 400 * 192);
            aq[0][0] = MFMA(x0, wq0, aq[0][0], 0, 0, 0);
            aq[1][0] = MFMA(x1, wq0, aq[1][0], 0, 0, 0);
            aq[0][1] = MFMA(x0, wq1, aq[0][1], 0, 0, 0);
            aq[1][1] = MFMA(x1, wq1, aq[1][1], 0, 0, 0);
            ak[0][0] = MFMA(x0, wk0, ak[0][0], 0, 0, 0);
            ak[1][0] = MFMA(x1, wk0, ak[1][0], 0, 0, 0);
            ak[0][1] = MFMA(x0, wk1, ak[0][1], 0, 0, 0);
            ak[1][1] = MFMA(x1, wk1, ak[1][1], 0, 0, 0);
            va[half * 2 + 0][0] = MFMA(x0, wv0, va[half * 2 + 0][0], 0, 0, 0);
            va[half * 2 + 1][0] = MFMA(x1, wv0, va[half * 2 + 1][0], 0, 0, 0);
            va[half * 2 + 0][1] = MFMA(x0, wv1, va[half * 2 + 0][1], 0, 0, 0);
            va[half * 2 + 1][1] = MFMA(x1, wv1, va[half * 2 + 1][1], 0, 0, 0);
        }
        float bq0 = qkv_b[h * 32 + lr],       bq1 = qkv_b[h * 32 + 16 + lr];
        float bk0 = qkv_b[192 + h * 32 + lr], bk1 = qkv_b[192 + h * 32 + 16 + lr];
#pragma unroll
        for (int mt2 = 0; mt2 < 2; ++mt2)
#pragma unroll
            for (int r = 0; r < 4; ++r) {
                int tok = half * 32 + mt2 * 16 + quad * 4 + r;
                R[tok * 40 + lr]       = (bf16_t)((aq[mt2][0][r] + bq0) * SCALE);
                R[tok * 40 + 16 + lr]  = (bf16_t)((aq[mt2][1][r] + bq1) * SCALE);
                RK[tok * 40 + lr]      = (bf16_t)(ak[mt2][0][r] + bk0);
                RK[tok * 40 + 16 + lr] = (bf16_t)(ak[mt2][1][r] + bk1);
            }
    }

    // ---- pull q,k fragments; then park vT in the dead k region ----
    bf16x8 qf[4], kf[4];
#pragma unroll
    for (int t = 0; t < 4; ++t) {
        qf[t] = *(const bf16x8*)&R[(t * 16 + lr) * 40 + quad * 8];
        kf[t] = *(const bf16x8*)&RK[(t * 16 + lr) * 40 + quad * 8];
    }
    {
        float bv0 = qkv_b[384 + h * 32 + lr], bv1 = qkv_b[384 + h * 32 + 16 + lr];
#pragma unroll
        for (int mt = 0; mt < 4; ++mt) {
            bf16x4 p0, p1;
#pragma unroll
            for (int r = 0; r < 4; ++r) {
                p0[r] = (bf16_t)(va[mt][0][r] + bv0);
                p1[r] = (bf16_t)(va[mt][1][r] + bv1);
            }
            *(bf16x4*)&RK[lr * 72 + mt * 16 + quad * 4]        = p0;  // vT[d][tok]
            *(bf16x4*)&RK[(16 + lr) * 72 + mt * 16 + quad * 4] = p1;
        }
    }

    // ---- QK^T (64x64, K=32) ----
    floatx4 s[4][4];
#pragma unroll
    for (int mt = 0; mt < 4; ++mt)
#pragma unroll
        for (int nt = 0; nt < 4; ++nt) s[mt][nt] = floatx4{0.f,0.f,0.f,0.f};
#pragma unroll
    for (int mt = 0; mt < 4; ++mt)
#pragma unroll
        for (int nt = 0; nt < 4; ++nt)
            s[mt][nt] = MFMA(qf[mt], kf[nt], s[mt][nt], 0, 0, 0);

    // bias + mask (C-frag ordered)
    const bf16_t* cb = cb2 + (((size_t)wh * 4) * 64 + lane) * 16;
#pragma unroll
    for (int mt = 0; mt < 4; ++mt) {
        bf16x8 c0 = *(const bf16x8*)(cb + (size_t)mt * 1024);
        bf16x8 c1 = *(const bf16x8*)(cb + (size_t)mt * 1024 + 8);
#pragma unroll
        for (int r = 0; r < 4; ++r) {
            s[mt][0][r] += (float)c0[r];
            s[mt][1][r] += (float)c0[4 + r];
            s[mt][2][r] += (float)c1[r];
            s[mt][3][r] += (float)c1[4 + r];
        }
    }

    // in-register row softmax (row spread over 16 lr lanes x 4 nt regs)
#pragma unroll
    for (int mt = 0; mt < 4; ++mt) {
#pragma unroll
        for (int r = 0; r < 4; ++r) {
            float mx = fmaxf(fmaxf(s[mt][0][r], s[mt][1][r]),
                             fmaxf(s[mt][2][r], s[mt][3][r]));
#pragma unroll
            for (int off = 1; off < 16; off <<= 1)
                mx = fmaxf(mx, __shfl_xor(mx, off));
            float sum = 0.f;
#pragma unroll
            for (int nt = 0; nt < 4; ++nt) {
                float e = __expf(s[mt][nt][r] - mx);
                s[mt][nt][r] = e; sum += e;
            }
#pragma unroll
            for (int off = 1; off < 16; off <<= 1)
                sum += __shfl_xor(sum, off);
            float inv = 1.0f / sum;
#pragma unroll
            for (int nt = 0; nt < 4; ++nt) s[mt][nt][r] *= inv;
        }
    }

    // ---- P -> q region in two 32-key halves; pull pf between (DS in-order) ----
#pragma unroll
    for (int mt = 0; mt < 4; ++mt)
#pragma unroll
        for (int nt = 0; nt < 2; ++nt)
#pragma unroll
            for (int r = 0; r < 4; ++r)
                R[(mt * 16 + quad * 4 + r) * 40 + nt * 16 + lr] = (bf16_t)s[mt][nt][r];
    bf16x8 pf0[4];
#pragma unroll
    for (int mt = 0; mt < 4; ++mt)
        pf0[mt] = *(const bf16x8*)&R[(mt * 16 + lr) * 40 + quad * 8];
#pragma unroll
    for (int mt = 0; mt < 4; ++mt)
#pragma unroll
        for (int nt = 2; nt < 4; ++nt)
#pragma unroll
            for (int r = 0; r < 4; ++r)
                R[(mt * 16 + quad * 4 + r) * 40 + (nt - 2) * 16 + lr] = (bf16_t)s[mt][nt][r];
    bf16x8 pf1[4];
#pragma unroll
    for (int mt = 0; mt < 4; ++mt)
        pf1[mt] = *(const bf16x8*)&R[(mt * 16 + lr) * 40 + quad * 8];

    // ---- PV (64 x 32, K=64) ----
    bf16x8 vf[2][2];
#pragma unroll
    for (int nt = 0; nt < 2; ++nt)
#pragma unroll
        for (int kt = 0; kt < 2; ++kt)
            vf[nt][kt] = *(const bf16x8*)&RK[(nt * 16 + lr) * 72 + kt * 32 + quad * 8];
    floatx4 c[4][2];
#pragma unroll
    for (int mt = 0; mt < 4; ++mt) { c[mt][0] = floatx4{0.f,0.f,0.f,0.f}; c[mt][1] = floatx4{0.f,0.f,0.f,0.f}; }
#pragma unroll
    for (int mt = 0; mt < 4; ++mt)
#pragma unroll
        for (int nt = 0; nt < 2; ++nt) {
            c[mt][nt] = MFMA(pf0[mt], vf[nt][0], c[mt][nt], 0, 0, 0);
            c[mt][nt] = MFMA(pf1[mt], vf[nt][1], c[mt][nt], 0, 0, 0);
        }

    // ---- ctx -> shared [64][200] (overlays head regions 0-2) ----
    __syncthreads();
#pragma unroll
    for (int mt = 0; mt < 4; ++mt)
#pragma unroll
        for (int nt = 0; nt < 2; ++nt)
#pragma unroll
            for (int r = 0; r < 4; ++r)
                lds[(mt * 16 + quad * 4 + r) * 200 + h * 32 + nt * 16 + lr] = (bf16_t)c[mt][nt][r];
    __syncthreads();

    // ---- proj: ctx[64x192] @ proj_w -> cols [h*32, h*32+32) ----
    const bf16_t* pw = wcvt + 110592;
    floatx4 pr[4][2];
#pragma unroll
    for (int mt = 0; mt < 4; ++mt) { pr[mt][0] = floatx4{0.f,0.f,0.f,0.f}; pr[mt][1] = floatx4{0.f,0.f,0.f,0.f}; }
#pragma unroll
    for (int ks = 0; ks < 6; ++ks) {
        bf16x8 w0 = *(const bf16x8*)(pw + (size_t)(h * 32 + lr) * 192 + ks * 32 + quad * 8);
        bf16x8 w1 = *(const bf16x8*)(pw + (size_t)(h * 32 + 16 + lr) * 192 + ks * 32 + quad * 8);
#pragma unroll
        for (int mt = 0; mt < 4; ++mt) {
            bf16x8 af = *(const bf16x8*)&lds[(mt * 16 + lr) * 200 + ks * 32 + quad * 8];
            pr[mt][0] = MFMA(af, w0, pr[mt][0], 0, 0, 0);
            pr[mt][1] = MFMA(af, w1, pr[mt][1], 0, 0, 0);
        }
    }
    // epilogue: bias + window-reverse + unshift scatter (only global write)
    {
        float pb0 = proj_b[h * 32 + lr], pb1 = proj_b[h * 32 + 16 + lr];
        int b = w >> 6, widx = w & 63;
        int whh = widx >> 3, www = widx & 7;
#pragma unroll
        for (int mt = 0; mt < 4; ++mt)
#pragma unroll
            for (int r = 0; r < 4; ++r) {
                int m = mt * 16 + quad * 4 + r;
                if (m < 49) {
                    int ii = m / 7, jj = m - ii * 7;
                    int hs = whh * 7 + ii + 3; if (hs >= 56) hs -= 56;
                    int ws2 = www * 7 + jj + 3; if (ws2 >= 56) ws2 -= 56;
                    size_t base = ((size_t)(b * 3136 + hs * 56 + ws2)) * 192 + h * 32;
                    pob[base + lr]      = (bf16_t)(pr[mt][0][r] + pb0);
                    pob[base + 16 + lr] = (bf16_t)(pr[mt][1][r] + pb1);
                }
            }
    }
}

// ---------------------------------------------------------------------------
// lin GEMM (LDS-free): out = resid + gelu(A @ lin_w^T + b), fp32 out.
// Block: 4 waves, tile 128m x 64n; wave tile 32m x 64n. grid (3, 784).
// ---------------------------------------------------------------------------
__global__ __launch_bounds__(256)
void lin_gemm(const bf16_t* __restrict__ A, const bf16_t* __restrict__ W,
              const float* __restrict__ bias, const float* __restrict__ resid,
              float* __restrict__ out)
{
    const int tid = threadIdx.x;
    const int wave = tid >> 6, lane = tid & 63;
    const int quad = lane >> 4, lr = lane & 15;
    const int n0 = blockIdx.x * 64;
    const int m0 = blockIdx.y * 128 + wave * 32;

    const bf16_t* a0p = A + (size_t)(m0 + lr) * 192 + quad * 8;
    const bf16_t* a1p = A + (size_t)(m0 + 16 + lr) * 192 + quad * 8;
    const bf16_t* w0p = W + (size_t)(n0 + lr) * 192 + quad * 8;
    const bf16_t* w1p = w0p + 16 * 192;
    const bf16_t* w2p = w0p + 32 * 192;
    const bf16_t* w3p = w0p + 48 * 192;

    floatx4 acc[2][4];
#pragma unroll
    for (int mt = 0; mt < 2; ++mt)
#pragma unroll
        for (int nt = 0; nt < 4; ++nt) acc[mt][nt] = floatx4{0.f,0.f,0.f,0.f};

#pragma unroll
    for (int ks = 0; ks < 6; ++ks) {
        bf16x8 af0 = *(const bf16x8*)(a0p + ks * 32);
        bf16x8 af1 = *(const bf16x8*)(a1p + ks * 32);
        bf16x8 wf0 = *(const bf16x8*)(w0p + ks * 32);
        bf16x8 wf1 = *(const bf16x8*)(w1p + ks * 32);
        bf16x8 wf2 = *(const bf16x8*)(w2p + ks * 32);
        bf16x8 wf3 = *(const bf16x8*)(w3p + ks * 32);
        acc[0][0] = MFMA(af0, wf0, acc[0][0], 0, 0, 0);
        acc[1][0] = MFMA(af1, wf0, acc[1][0], 0, 0, 0);
        acc[0][1] = MFMA(af0, wf1, acc[0][1], 0, 0, 0);
        acc[1][1] = MFMA(af1, wf1, acc[1][1], 0, 0, 0);
        acc[0][2] = MFMA(af0, wf2, acc[0][2], 0, 0, 0);
        acc[1][2] = MFMA(af1, wf2, acc[1][2], 0, 0, 0);
        acc[0][3] = MFMA(af0, wf3, acc[0][3], 0, 0, 0);
        acc[1][3] = MFMA(af1, wf3, acc[1][3], 0, 0, 0);
    }

#pragma unroll
    for (int mt = 0; mt < 2; ++mt)
#pragma unroll
    for (int nt = 0; nt < 4; ++nt) {
        int n = n0 + nt * 16 + lr;
        float bv = bias[n];
#pragma unroll
        for (int r = 0; r < 4; ++r) {
            int m = m0 + mt * 16 + quad * 4 + r;
            float val = acc[mt][nt][r] + bv;
            float gx = 0.5f * val * (1.0f + erff(val * 0.70710678118654752f));
            out[(size_t)m * 192 + n] = resid[(size_t)m * 192 + n] + gx;
        }
    }
}

// ---------------------------------------------------------------------------
extern "C" void kernel_launch(void* const* d_in, const int* in_sizes, int n_in,
                              void* d_out, int out_size, void* d_ws, size_t ws_size,
                              hipStream_t stream)
{
    const float* inp    = (const float*)d_in[0];
    const float* mask   = (const float*)d_in[1];
    const float* g      = (const float*)d_in[2];
    const float* bta    = (const float*)d_in[3];
    const float* qkv_w  = (const float*)d_in[4];
    const float* qkv_b  = (const float*)d_in[5];
    const float* table  = (const float*)d_in[6];
    const int*   rpi    = (const int*)d_in[7];
    const float* proj_w = (const float*)d_in[8];
    const float* proj_b = (const float*)d_in[9];
    const float* lin_w  = (const float*)d_in[10];
    const float* lin_b  = (const float*)d_in[11];
    float* out = (float*)d_out;

    char* ws = (char*)d_ws;
    bf16_t* xw   = (bf16_t*)(ws);                 // 38,535,168 B (+64-row slack)
    bf16_t* pob  = (bf16_t*)(ws + 40000000);      // 38,535,168 B
    bf16_t* wcvt = (bf16_t*)(ws + 80000000);      //    368,640 B
    bf16_t* cb2  = (bf16_t*)(ws + 80400000);      //  3,145,728 B  (end ~83.5 MB)

    convert_weights<<<720, 256, 0, stream>>>(qkv_w, proj_w, lin_w, wcvt);
    build_cb2<<<6144, 256, 0, stream>>>(table, rpi, mask, cb2);
    ln_window<<<25088, 256, 0, stream>>>(inp, g, bta, xw);
    fused_window<<<2048, 384, 0, stream>>>(xw, wcvt, qkv_b, proj_b, cb2, pob);
    lin_gemm<<<dim3(3, 784), 256, 0, stream>>>(pob, wcvt + 147456, lin_b, inp, out);
}

// Round 3
// 433.414 us; speedup vs baseline: 1.0689x; 1.0689x over previous
//
#include <hip/hip_runtime.h>
#include <hip/hip_bf16.h>
#include <math.h>

typedef __bf16 bf16_t;
typedef __attribute__((ext_vector_type(4))) __bf16 bf16x4;
typedef __attribute__((ext_vector_type(8))) __bf16 bf16x8;
typedef __attribute__((ext_vector_type(4))) float floatx4;

#define SCALE 0.17677669529663689f
#define MFMA __builtin_amdgcn_mfma_f32_16x16x32_bf16

// ---------------------------------------------------------------------------
// LayerNorm + cyclic shift (-3,-3) + window partition; fp32 in -> bf16 out
// ---------------------------------------------------------------------------
__global__ __launch_bounds__(256)
void ln_window(const float* __restrict__ x, const float* __restrict__ g,
               const float* __restrict__ bta, bf16_t* __restrict__ xw)
{
    const int wv = threadIdx.x >> 6, lane = threadIdx.x & 63;
    const int t = blockIdx.x * 4 + wv;            // token id, < 100352
    const float* row = x + (size_t)t * 192;
    float v0 = row[lane];
    float v1 = row[lane + 64];
    float v2 = row[lane + 128];
    float s  = v0 + v1 + v2;
    float sq = v0 * v0 + v1 * v1 + v2 * v2;
#pragma unroll
    for (int off = 32; off > 0; off >>= 1) {
        s  += __shfl_down(s, off);
        sq += __shfl_down(sq, off);
    }
    s = __shfl(s, 0); sq = __shfl(sq, 0);
    float mu  = s * (1.0f / 192.0f);
    float var = sq * (1.0f / 192.0f) - mu * mu;
    float inv = rsqrtf(var + 1e-5f);

    int b = t / 3136, p = t - b * 3136;
    int hh = p / 56, ww = p - hh * 56;
    int hs = hh - 3; if (hs < 0) hs += 56;
    int ws = ww - 3; if (ws < 0) ws += 56;
    int wh = hs / 7, ii = hs - wh * 7;
    int wwi = ws / 7, jj = ws - wwi * 7;
    size_t orow = ((size_t)(b * 64 + wh * 8 + wwi) * 49 + ii * 7 + jj) * 192;

    xw[orow + lane]       = (bf16_t)((v0 - mu) * inv * g[lane]       + bta[lane]);
    xw[orow + lane + 64]  = (bf16_t)((v1 - mu) * inv * g[lane + 64]  + bta[lane + 64]);
    xw[orow + lane + 128] = (bf16_t)((v2 - mu) * inv * g[lane + 128] + bta[lane + 128]);
}

// ---------------------------------------------------------------------------
// Weight fp32 -> bf16 conversion (qkv_w | proj_w | lin_w concatenated)
// ---------------------------------------------------------------------------
__global__ __launch_bounds__(256)
void convert_weights(const float* __restrict__ a, const float* __restrict__ b,
                     const float* __restrict__ c, bf16_t* __restrict__ out)
{
    int i = blockIdx.x * 256 + threadIdx.x;   // 184320 total
    if (i < 110592)       out[i] = (bf16_t)a[i];
    else if (i < 147456)  out[i] = (bf16_t)b[i - 110592];
    else                  out[i] = (bf16_t)c[i - 147456];
}

// ---------------------------------------------------------------------------
// Pre-combine rel-pos bias + shift mask into C-fragment-ordered table:
// cb2[wh=win*6+h][mt][lane][nt*4+r]  (bf16); j>=49 -> -1e30
// ---------------------------------------------------------------------------
__global__ __launch_bounds__(256)
void build_cb2(const float* __restrict__ table, const int* __restrict__ rpi,
               const float* __restrict__ mask, bf16_t* __restrict__ cb2)
{
    int i = blockIdx.x * 256 + threadIdx.x;   // 1,572,864 total
    int idx = i & 15, lane = (i >> 4) & 63, mt = (i >> 10) & 3, wh = i >> 12;
    int win = wh / 6, h = wh - win * 6;
    int nt = idx >> 2, r = idx & 3;
    int m = mt * 16 + ((lane >> 4)) * 4 + r;
    int j = nt * 16 + (lane & 15);
    float v;
    if (j >= 49)      v = -1e30f;
    else if (m >= 49) v = 0.0f;
    else              v = table[rpi[m * 49 + j] * 6 + h] + mask[win * 2401 + m * 49 + j];
    cb2[i] = (bf16_t)v;
}

// ---------------------------------------------------------------------------
// Fused per-window kernel: qkv GEMM + attention + proj GEMM.
// One block per window (2048), 12 WAVES (768 thr): wave (h, mh) = head h,
// token-half mh (rows mh*32..mh*32+31).  Round-1 lesson: block residency is
// pinned at 1 block/CU regardless of VGPR (LDS-limited), so raise waves/CU
// by doubling waves/block: 6 -> 12 waves = 3 waves/SIMD.
//
// LDS: 6 regions of 5120 bf16 (10.24 KB) = 60 KB total.
//   region/head: [q 64x40 | k 64x40];  vT [32][72] overlays k after kf pulls
//   (barrier-protected, k is read cross-wave); P overlays q rows (wave-own);
//   ctx overlays q rows [64][40] per head region; proj reads all regions.
// Barriers: qk-stored / frags-pulled / vT-ready / ctx-ready.
// ---------------------------------------------------------------------------
__global__ __launch_bounds__(768, 3)
void fused_window(const bf16_t* __restrict__ xw, const bf16_t* __restrict__ wcvt,
                  const float* __restrict__ qkv_b, const float* __restrict__ proj_b,
                  const bf16_t* __restrict__ cb2, bf16_t* __restrict__ pob)
{
    __shared__ __align__(16) bf16_t lds[30720];     // 6 * 5120
    const int tid = threadIdx.x;
    const int wv = tid >> 6;                         // wave 0..11
    const int h = wv >> 1;                           // head 0..5
    const int mh = wv & 1;                           // token half 0..1
    const int lane = tid & 63;
    const int quad = lane >> 4, lr = lane & 15;
    const int w = blockIdx.x;                        // window id 0..2047
    const int wh = (w & 63) * 6 + h;
    bf16_t* R  = lds + h * 5120;                     // q rows [64][40]
    bf16_t* RK = R + 2560;                           // k rows [64][40] -> vT [32][72]

    const bf16_t* xb = xw + (size_t)w * 49 * 192;

    // ---- X A-fragments for this wave's 32 tokens (persist through phase A) ----
    bf16x8 xf[2][6];
#pragma unroll
    for (int mt2 = 0; mt2 < 2; ++mt2)
#pragma unroll
        for (int ks = 0; ks < 6; ++ks)
            xf[mt2][ks] = *(const bf16x8*)(xb + (size_t)(mh * 32 + mt2 * 16 + lr) * 192 + ks * 32 + quad * 8);

    // ---- Pass 1: q,k = X @ Wq,Wk for own 32 tokens ----
    floatx4 aq[2][2], ak[2][2];
#pragma unroll
    for (int mt2 = 0; mt2 < 2; ++mt2)
#pragma unroll
        for (int nt = 0; nt < 2; ++nt) {
            aq[mt2][nt] = floatx4{0.f,0.f,0.f,0.f};
            ak[mt2][nt] = floatx4{0.f,0.f,0.f,0.f};
        }
#pragma unroll
    for (int ks = 0; ks < 6; ++ks) {
        const bf16_t* wr = wcvt + (size_t)(h * 32 + lr) * 192 + ks * 32 + quad * 8;
        bf16x8 wq0 = *(const bf16x8*)(wr);
        bf16x8 wq1 = *(const bf16x8*)(wr + 16 * 192);
        bf16x8 wk0 = *(const bf16x8*)(wr + 192 * 192);
        bf16x8 wk1 = *(const bf16x8*)(wr + 208 * 192);
#pragma unroll
        for (int mt2 = 0; mt2 < 2; ++mt2) {
            aq[mt2][0] = MFMA(xf[mt2][ks], wq0, aq[mt2][0], 0, 0, 0);
            aq[mt2][1] = MFMA(xf[mt2][ks], wq1, aq[mt2][1], 0, 0, 0);
            ak[mt2][0] = MFMA(xf[mt2][ks], wk0, ak[mt2][0], 0, 0, 0);
            ak[mt2][1] = MFMA(xf[mt2][ks], wk1, ak[mt2][1], 0, 0, 0);
        }
    }
    {
        float bq0 = qkv_b[h * 32 + lr],       bq1 = qkv_b[h * 32 + 16 + lr];
        float bk0 = qkv_b[192 + h * 32 + lr], bk1 = qkv_b[192 + h * 32 + 16 + lr];
#pragma unroll
        for (int mt2 = 0; mt2 < 2; ++mt2)
#pragma unroll
            for (int r = 0; r < 4; ++r) {
                int tok = mh * 32 + mt2 * 16 + quad * 4 + r;
                R[tok * 40 + lr]       = (bf16_t)((aq[mt2][0][r] + bq0) * SCALE);
                R[tok * 40 + 16 + lr]  = (bf16_t)((aq[mt2][1][r] + bq1) * SCALE);
                RK[tok * 40 + lr]      = (bf16_t)(ak[mt2][0][r] + bk0);
                RK[tok * 40 + 16 + lr] = (bf16_t)(ak[mt2][1][r] + bk1);
            }
    }
    __syncthreads();   // q,k staged by both waves of each head

    // ---- pull q (own rows), k (all 64 rows) fragments ----
    bf16x8 qf[2], kf[4];
#pragma unroll
    for (int mt2 = 0; mt2 < 2; ++mt2)
        qf[mt2] = *(const bf16x8*)&R[(mh * 32 + mt2 * 16 + lr) * 40 + quad * 8];
#pragma unroll
    for (int t = 0; t < 4; ++t)
        kf[t] = *(const bf16x8*)&RK[(t * 16 + lr) * 40 + quad * 8];
    __syncthreads();   // all kf pulled; k region may be overlaid by vT

    // ---- Pass 2: v = X @ Wv (reuses xf), park vT into dead k region ----
    {
        floatx4 av[2][2];
#pragma unroll
        for (int mt2 = 0; mt2 < 2; ++mt2) { av[mt2][0] = floatx4{0.f,0.f,0.f,0.f}; av[mt2][1] = floatx4{0.f,0.f,0.f,0.f}; }
#pragma unroll
        for (int ks = 0; ks < 6; ++ks) {
            const bf16_t* wr = wcvt + (size_t)(384 + h * 32 + lr) * 192 + ks * 32 + quad * 8;
            bf16x8 wv0 = *(const bf16x8*)(wr);
            bf16x8 wv1 = *(const bf16x8*)(wr + 16 * 192);
#pragma unroll
            for (int mt2 = 0; mt2 < 2; ++mt2) {
                av[mt2][0] = MFMA(xf[mt2][ks], wv0, av[mt2][0], 0, 0, 0);
                av[mt2][1] = MFMA(xf[mt2][ks], wv1, av[mt2][1], 0, 0, 0);
            }
        }
        float bv0 = qkv_b[384 + h * 32 + lr], bv1 = qkv_b[384 + h * 32 + 16 + lr];
#pragma unroll
        for (int mt2 = 0; mt2 < 2; ++mt2) {
            bf16x4 p0, p1;
#pragma unroll
            for (int r = 0; r < 4; ++r) {
                p0[r] = (bf16_t)(av[mt2][0][r] + bv0);
                p1[r] = (bf16_t)(av[mt2][1][r] + bv1);
            }
            *(bf16x4*)&RK[lr * 72 + mh * 32 + mt2 * 16 + quad * 4]        = p0;  // vT[d][tok]
            *(bf16x4*)&RK[(16 + lr) * 72 + mh * 32 + mt2 * 16 + quad * 4] = p1;
        }
    }

    // ---- QK^T for own 32 rows (32x64, K=32) ----
    floatx4 s[2][4];
#pragma unroll
    for (int mt2 = 0; mt2 < 2; ++mt2)
#pragma unroll
        for (int nt = 0; nt < 4; ++nt) s[mt2][nt] = floatx4{0.f,0.f,0.f,0.f};
#pragma unroll
    for (int mt2 = 0; mt2 < 2; ++mt2)
#pragma unroll
        for (int nt = 0; nt < 4; ++nt)
            s[mt2][nt] = MFMA(qf[mt2], kf[nt], s[mt2][nt], 0, 0, 0);

    // bias + mask (C-frag ordered); this wave covers global mt = mh*2 + mt2
    const bf16_t* cb = cb2 + (((size_t)wh * 4 + mh * 2) * 64 + lane) * 16;
#pragma unroll
    for (int mt2 = 0; mt2 < 2; ++mt2) {
        bf16x8 c0 = *(const bf16x8*)(cb + (size_t)mt2 * 1024);
        bf16x8 c1 = *(const bf16x8*)(cb + (size_t)mt2 * 1024 + 8);
#pragma unroll
        for (int r = 0; r < 4; ++r) {
            s[mt2][0][r] += (float)c0[r];
            s[mt2][1][r] += (float)c0[4 + r];
            s[mt2][2][r] += (float)c1[r];
            s[mt2][3][r] += (float)c1[4 + r];
        }
    }

    // in-register row softmax (row spread over 16 lr lanes x 4 nt regs)
#pragma unroll
    for (int mt2 = 0; mt2 < 2; ++mt2) {
#pragma unroll
        for (int r = 0; r < 4; ++r) {
            float mx = fmaxf(fmaxf(s[mt2][0][r], s[mt2][1][r]),
                             fmaxf(s[mt2][2][r], s[mt2][3][r]));
#pragma unroll
            for (int off = 1; off < 16; off <<= 1)
                mx = fmaxf(mx, __shfl_xor(mx, off));
            float sum = 0.f;
#pragma unroll
            for (int nt = 0; nt < 4; ++nt) {
                float e = __expf(s[mt2][nt][r] - mx);
                s[mt2][nt][r] = e; sum += e;
            }
#pragma unroll
            for (int off = 1; off < 16; off <<= 1)
                sum += __shfl_xor(sum, off);
            float inv = 1.0f / sum;
#pragma unroll
            for (int nt = 0; nt < 4; ++nt) s[mt2][nt][r] *= inv;
        }
    }

    // ---- P -> own q-region rows in two 32-key halves; pull pf between ----
#pragma unroll
    for (int mt2 = 0; mt2 < 2; ++mt2)
#pragma unroll
        for (int nt = 0; nt < 2; ++nt)
#pragma unroll
            for (int r = 0; r < 4; ++r)
                R[(mh * 32 + mt2 * 16 + quad * 4 + r) * 40 + nt * 16 + lr] = (bf16_t)s[mt2][nt][r];
    bf16x8 pf0[2];
#pragma unroll
    for (int mt2 = 0; mt2 < 2; ++mt2)
        pf0[mt2] = *(const bf16x8*)&R[(mh * 32 + mt2 * 16 + lr) * 40 + quad * 8];
#pragma unroll
    for (int mt2 = 0; mt2 < 2; ++mt2)
#pragma unroll
        for (int nt = 2; nt < 4; ++nt)
#pragma unroll
            for (int r = 0; r < 4; ++r)
                R[(mh * 32 + mt2 * 16 + quad * 4 + r) * 40 + (nt - 2) * 16 + lr] = (bf16_t)s[mt2][nt][r];
    bf16x8 pf1[2];
#pragma unroll
    for (int mt2 = 0; mt2 < 2; ++mt2)
        pf1[mt2] = *(const bf16x8*)&R[(mh * 32 + mt2 * 16 + lr) * 40 + quad * 8];

    __syncthreads();   // vT fully written by both waves of each head

    // ---- PV (32 x 32, K=64) ----
    bf16x8 vf[2][2];
#pragma unroll
    for (int nt = 0; nt < 2; ++nt)
#pragma unroll
        for (int kt = 0; kt < 2; ++kt)
            vf[nt][kt] = *(const bf16x8*)&RK[(nt * 16 + lr) * 72 + kt * 32 + quad * 8];
    floatx4 c[2][2];
#pragma unroll
    for (int mt2 = 0; mt2 < 2; ++mt2) { c[mt2][0] = floatx4{0.f,0.f,0.f,0.f}; c[mt2][1] = floatx4{0.f,0.f,0.f,0.f}; }
#pragma unroll
    for (int mt2 = 0; mt2 < 2; ++mt2)
#pragma unroll
        for (int nt = 0; nt < 2; ++nt) {
            c[mt2][nt] = MFMA(pf0[mt2], vf[nt][0], c[mt2][nt], 0, 0, 0);
            c[mt2][nt] = MFMA(pf1[mt2], vf[nt][1], c[mt2][nt], 0, 0, 0);
        }

    // ---- ctx -> own q-region rows [64][40] per head region ----
#pragma unroll
    for (int mt2 = 0; mt2 < 2; ++mt2)
#pragma unroll
        for (int nt = 0; nt < 2; ++nt)
#pragma unroll
            for (int r = 0; r < 4; ++r)
                R[(mh * 32 + mt2 * 16 + quad * 4 + r) * 40 + nt * 16 + lr] = (bf16_t)c[mt2][nt][r];
    __syncthreads();   // ctx of all heads staged

    // ---- proj: ctx[64x192] @ proj_w -> wave's 16 cols [wv*16, wv*16+16) ----
    const bf16_t* pw = wcvt + 110592;
    floatx4 pr[4];
#pragma unroll
    for (int mt = 0; mt < 4; ++mt) pr[mt] = floatx4{0.f,0.f,0.f,0.f};
#pragma unroll
    for (int ks = 0; ks < 6; ++ks) {
        bf16x8 w0 = *(const bf16x8*)(pw + (size_t)(wv * 16 + lr) * 192 + ks * 32 + quad * 8);
#pragma unroll
        for (int mt = 0; mt < 4; ++mt) {
            bf16x8 af = *(const bf16x8*)&lds[ks * 5120 + (mt * 16 + lr) * 40 + quad * 8];
            pr[mt] = MFMA(af, w0, pr[mt], 0, 0, 0);
        }
    }
    // epilogue: bias + window-reverse + unshift scatter (only global write)
    {
        float pb = proj_b[wv * 16 + lr];
        int b = w >> 6, widx = w & 63;
        int whh = widx >> 3, www = widx & 7;
#pragma unroll
        for (int mt = 0; mt < 4; ++mt)
#pragma unroll
            for (int r = 0; r < 4; ++r) {
                int m = mt * 16 + quad * 4 + r;
                if (m < 49) {
                    int ii = m / 7, jj = m - ii * 7;
                    int hs = whh * 7 + ii + 3; if (hs >= 56) hs -= 56;
                    int ws2 = www * 7 + jj + 3; if (ws2 >= 56) ws2 -= 56;
                    size_t base = ((size_t)(b * 3136 + hs * 56 + ws2)) * 192 + wv * 16;
                    pob[base + lr] = (bf16_t)(pr[mt][r] + pb);
                }
            }
    }
}

// ---------------------------------------------------------------------------
// lin GEMM (LDS-free): out = resid + gelu(A @ lin_w^T + b), fp32 out.
// Block: 4 waves, tile 128m x 64n; wave tile 32m x 64n. grid (3, 784).
// ---------------------------------------------------------------------------
__global__ __launch_bounds__(256)
void lin_gemm(const bf16_t* __restrict__ A, const bf16_t* __restrict__ W,
              const float* __restrict__ bias, const float* __restrict__ resid,
              float* __restrict__ out)
{
    const int tid = threadIdx.x;
    const int wave = tid >> 6, lane = tid & 63;
    const int quad = lane >> 4, lr = lane & 15;
    const int n0 = blockIdx.x * 64;
    const int m0 = blockIdx.y * 128 + wave * 32;

    const bf16_t* a0p = A + (size_t)(m0 + lr) * 192 + quad * 8;
    const bf16_t* a1p = A + (size_t)(m0 + 16 + lr) * 192 + quad * 8;
    const bf16_t* w0p = W + (size_t)(n0 + lr) * 192 + quad * 8;
    const bf16_t* w1p = w0p + 16 * 192;
    const bf16_t* w2p = w0p + 32 * 192;
    const bf16_t* w3p = w0p + 48 * 192;

    floatx4 acc[2][4];
#pragma unroll
    for (int mt = 0; mt < 2; ++mt)
#pragma unroll
        for (int nt = 0; nt < 4; ++nt) acc[mt][nt] = floatx4{0.f,0.f,0.f,0.f};

#pragma unroll
    for (int ks = 0; ks < 6; ++ks) {
        bf16x8 af0 = *(const bf16x8*)(a0p + ks * 32);
        bf16x8 af1 = *(const bf16x8*)(a1p + ks * 32);
        bf16x8 wf0 = *(const bf16x8*)(w0p + ks * 32);
        bf16x8 wf1 = *(const bf16x8*)(w1p + ks * 32);
        bf16x8 wf2 = *(const bf16x8*)(w2p + ks * 32);
        bf16x8 wf3 = *(const bf16x8*)(w3p + ks * 32);
        acc[0][0] = MFMA(af0, wf0, acc[0][0], 0, 0, 0);
        acc[1][0] = MFMA(af1, wf0, acc[1][0], 0, 0, 0);
        acc[0][1] = MFMA(af0, wf1, acc[0][1], 0, 0, 0);
        acc[1][1] = MFMA(af1, wf1, acc[1][1], 0, 0, 0);
        acc[0][2] = MFMA(af0, wf2, acc[0][2], 0, 0, 0);
        acc[1][2] = MFMA(af1, wf2, acc[1][2], 0, 0, 0);
        acc[0][3] = MFMA(af0, wf3, acc[0][3], 0, 0, 0);
        acc[1][3] = MFMA(af1, wf3, acc[1][3], 0, 0, 0);
    }

#pragma unroll
    for (int mt = 0; mt < 2; ++mt)
#pragma unroll
    for (int nt = 0; nt < 4; ++nt) {
        int n = n0 + nt * 16 + lr;
        float bv = bias[n];
#pragma unroll
        for (int r = 0; r < 4; ++r) {
            int m = m0 + mt * 16 + quad * 4 + r;
            float val = acc[mt][nt][r] + bv;
            float gx = 0.5f * val * (1.0f + erff(val * 0.70710678118654752f));
            out[(size_t)m * 192 + n] = resid[(size_t)m * 192 + n] + gx;
        }
    }
}

// ---------------------------------------------------------------------------
extern "C" void kernel_launch(void* const* d_in, const int* in_sizes, int n_in,
                              void* d_out, int out_size, void* d_ws, size_t ws_size,
                              hipStream_t stream)
{
    const float* inp    = (const float*)d_in[0];
    const float* mask   = (const float*)d_in[1];
    const float* g      = (const float*)d_in[2];
    const float* bta    = (const float*)d_in[3];
    const float* qkv_w  = (const float*)d_in[4];
    const float* qkv_b  = (const float*)d_in[5];
    const float* table  = (const float*)d_in[6];
    const int*   rpi    = (const int*)d_in[7];
    const float* proj_w = (const float*)d_in[8];
    const float* proj_b = (const float*)d_in[9];
    const float* lin_w  = (const float*)d_in[10];
    const float* lin_b  = (const float*)d_in[11];
    float* out = (float*)d_out;

    char* ws = (char*)d_ws;
    bf16_t* xw   = (bf16_t*)(ws);                 // 38,535,168 B (+64-row slack)
    bf16_t* pob  = (bf16_t*)(ws + 40000000);      // 38,535,168 B
    bf16_t* wcvt = (bf16_t*)(ws + 80000000);      //    368,640 B
    bf16_t* cb2  = (bf16_t*)(ws + 80400000);      //  3,145,728 B  (end ~83.5 MB)

    convert_weights<<<720, 256, 0, stream>>>(qkv_w, proj_w, lin_w, wcvt);
    build_cb2<<<6144, 256, 0, stream>>>(table, rpi, mask, cb2);
    ln_window<<<25088, 256, 0, stream>>>(inp, g, bta, xw);
    fused_window<<<2048, 768, 0, stream>>>(xw, wcvt, qkv_b, proj_b, cb2, pob);
    lin_gemm<<<dim3(3, 784), 256, 0, stream>>>(pob, wcvt + 147456, lin_b, inp, out);
}